// Round 8
// baseline (1196.473 us; speedup 1.0000x reference)
//
#include <hip/hip_runtime.h>
#include <hip/hip_fp8.h>
#include <cstdint>
#include <cstddef>

// Problem dims (TemporalLSTM_77455440216810)
// r8: r7 + (1) h@U (2/3 of gate K) hoisted into P0, overlapped with cUa/Wa
// staging -- only ctx@W (K=128) left on the critical path after softmax;
// (2) Wa pre-repacked to fp8 frags (P0 staging = 8KB coalesced copy);
// (3) softmax max-pass removed (logits bounded ~0.2; softmax shift-inv),
// sum fused into P1 epilogue. Barriers 10 -> 5 per step.
#define IDIM 128   // INPUT_DIM
#define HS   256   // HIDDEN
#define SEQL 512   // SEQ
#define TOUT 24    // OUT (scan steps)
#define TMP  64    // TEMP
#define NB   512   // B
#define G4   1024  // 4*HS

typedef unsigned short u16;
typedef unsigned int   u32;
typedef __attribute__((ext_vector_type(4))) float f32x4;     // MFMA C/D frag
typedef _Float16 f16x8 __attribute__((ext_vector_type(8)));  // f16 MFMA A/B frag

// ---- LDS layout (bytes). ONE batch element per 512-thr WG. Total 81768;
// ---- 2 x 81768 = 163536 <= 163840 -> 2 WGs/CU.
#define OFF_HFRAG 0        // 65536: 512x128 fp8 MFMA-A frags
#define OFF_GATEP 65536    // 8192: Wa fp8 B-frags UNION gates f32[1024] (4KB)
                           //       UNION (WBF=0) gate partials u32[2][512]
#define OFF_E     73728    // 2048: e[512] f32 (holds pv = exp2(e/16*log2e))
#define OFF_CUAP  75776    // 2048: cua partials [8][64] f32
                           //       UNION ctx partials [2][128] f32
#define OFF_H     77824    // 1024: h[256] f32 (fallback path only)
#define OFF_C     78848    // 1024: c[256] f32
#define OFF_CTX   79872    // 512:  ctx[128] f32 (fallback path only)
#define OFF_CUABA 80384    // 256:  (unused; cb computed inline)
#define OFF_VA    80640    // 256:  (unused; Va read inline)
#define OFF_RED   80896    // 96:   reduction scratch [24] f32
#define OFF_Y     80992    // 4
#define OFF_INVD  80996    // 4
#define OFF_AB    81000    // 768:  packed f16 [ctx(64)|h(128)] pairs u32[192]
#define SMEM_BYTES 81768

__device__ __forceinline__ u16 f2bf(float f) {            // RNE f32->bf16
  union { float f; u32 u; } v; v.f = f;
  u32 r = v.u + 0x7FFFu + ((v.u >> 16) & 1u);
  return (u16)(r >> 16);
}
__device__ __forceinline__ float bflo(u32 u) {
  union { u32 u; float f; } v; v.u = u << 16; return v.f;
}
__device__ __forceinline__ float bfhi(u32 u) {
  union { u32 u; float f; } v; v.u = u & 0xFFFF0000u; return v.f;
}
__device__ __forceinline__ u32 pkbf(float a, float b) {
  return (u32)f2bf(a) | ((u32)f2bf(b) << 16);
}
__device__ __forceinline__ u32 pkf16(float a, float b) {  // 2 x f32 -> packed f16 (RNE)
  union { _Float16 h[2]; u32 u; } v;
  v.h[0] = (_Float16)a; v.h[1] = (_Float16)b; return v.u;
}
// fp8 e4m3 (OCP) pack/unpack
__device__ __forceinline__ u32 pk4_fp8(float a, float b, float c, float d) {
#if __has_builtin(__builtin_amdgcn_cvt_pk_fp8_f32)
  u32 v = (u32)__builtin_amdgcn_cvt_pk_fp8_f32(a, b, 0, false);
  v = (u32)__builtin_amdgcn_cvt_pk_fp8_f32(c, d, (int)v, true);
  return v;
#else
  __hip_fp8_e4m3 x(a), y(b), z(c), w(d);
  return (u32)x.__x | ((u32)y.__x << 8) | ((u32)z.__x << 16) | ((u32)w.__x << 24);
#endif
}
template <int S>
__device__ __forceinline__ float fp8_f32(u32 v) {
#if __has_builtin(__builtin_amdgcn_cvt_f32_fp8)
  return __builtin_amdgcn_cvt_f32_fp8((int)v, S);
#else
  __hip_fp8_e4m3 x; x.__x = (unsigned char)(v >> (8 * S)); return (float)x;
#endif
}
// Pade(3/2) tanh for attention scores (error attenuated by Va-dot + /16 + softmax)
__device__ __forceinline__ float tanh_fast(float x) {
  float x2 = x * x;
  float r = x * (27.0f + x2) * __builtin_amdgcn_rcpf(27.0f + 9.0f * x2);
  return fminf(fmaxf(r, -1.0f), 1.0f);
}
__device__ __forceinline__ float sigmoid_acc(float x) {
  return __builtin_amdgcn_rcpf(1.0f + __builtin_exp2f(-1.4426950408889634f * x));
}
__device__ __forceinline__ float tanh_acc(float x) {
  return 1.0f - 2.0f * __builtin_amdgcn_rcpf(1.0f + __builtin_exp2f(2.8853900817779268f * x));
}

// Repack W[128][24][1024] + U[256][24][1024] (f32) into f16 MFMA-B frags:
// frag f = ((t*64 + nt)*12 + kc)*64 + lane holds 8 f16: n = nt*16+(lane&15),
// k = kc*32 + (lane>>4)*8 + j;  k<128 -> W[k] (ctx), else U[k-128] (h).
__global__ void repack_f16_kernel(const float* __restrict__ W, const float* __restrict__ U,
                                  u32* __restrict__ WUf) {
  int f = blockIdx.x * blockDim.x + threadIdx.x;   // 0..1179647
  if (f >= TOUT * 64 * 12 * 64) return;
  int lane = f & 63;
  int kc = (f >> 6) % 12;
  int nt = (f / (64 * 12)) % 64;
  int t = f / (64 * 12 * 64);
  int lm = lane & 15, q = lane >> 4;
  int n = nt * 16 + lm;
  int kb = kc * 32 + q * 8;
  u32 w4[4];
#pragma unroll
  for (int jj = 0; jj < 4; ++jj) {
    int k0 = kb + 2 * jj, k1 = k0 + 1;
    float v0 = (k0 < 128) ? W[((size_t)k0 * TOUT + t) * G4 + n]
                          : U[((size_t)(k0 - 128) * TOUT + t) * G4 + n];
    float v1 = (k1 < 128) ? W[((size_t)k1 * TOUT + t) * G4 + n]
                          : U[((size_t)(k1 - 128) * TOUT + t) * G4 + n];
    w4[jj] = pkf16(v0, v1);
  }
  *(uint4*)(WUf + (size_t)f * 4) = make_uint4(w4[0], w4[1], w4[2], w4[3]);
}

// Repack Wa[128][24][64] into fp8 B-frags: frag (t, nt, kc) at
// ((t*4 + nt)*4 + kc)*64 + lane (uint2): n = nt*16+(lane&15),
// k = kc*32+(lane>>4)*8+j.
__global__ void repack_wa_kernel(const float* __restrict__ Wa, u32* __restrict__ WaF8) {
  int f = blockIdx.x * blockDim.x + threadIdx.x;   // 0..24575
  if (f >= TOUT * 16 * 64) return;
  int lane = f & 63;
  int fr = (f >> 6) & 15;      // nt*4+kc
  int t = f >> 10;
  int nt = fr >> 2, kc = fr & 3;
  int lm = lane & 15, q = lane >> 4;
  int n = nt * 16 + lm;
  float v[8];
#pragma unroll
  for (int j = 0; j < 8; ++j) {
    int k = kc * 32 + q * 8 + j;
    v[j] = Wa[((size_t)k * TOUT + t) * TMP + n];
  }
  *(uint2*)(WaF8 + (size_t)f * 2) =
      make_uint2(pk4_fp8(v[0], v[1], v[2], v[3]), pk4_fp8(v[4], v[5], v[6], v[7]));
}

// Persistent kernel: one WG (512 thr) = ONE batch element, all 24 steps.
// 512 WGs -> 2 WGs/CU. Gate GEMM f16 MFMA; h@U part (K=256) runs in P0
// overlapped with attention prep; ctx@W (K=128) after softmax.
template <int WBF>
__global__ __launch_bounds__(512, 4) void lstm_attn_kernel(
    const float* __restrict__ H, const float* __restrict__ y0, const float* __restrict__ emb,
    const float* __restrict__ Wa, const float* __restrict__ UaF, const float* __restrict__ ba,
    const float* __restrict__ Va, const float* __restrict__ WF, const float* __restrict__ UF,
    const float* __restrict__ bias, const float* __restrict__ WyF, const float* __restrict__ fcw,
    const float* __restrict__ fcb, const u32* __restrict__ WUf, const u32* __restrict__ WaF8,
    float* __restrict__ out) {
  const int bg = blockIdx.x;
  const int tid = threadIdx.x;        // 0..511
  const int lane = tid & 63;
  const int wv = tid >> 6;            // 0..7
  extern __shared__ char smem[];
  float* eL     = (float*)(smem + OFF_E);
  float* hL     = (float*)(smem + OFF_H);
  float* cL     = (float*)(smem + OFF_C);
  float* ctxL   = (float*)(smem + OFF_CTX);
  float* cuapL  = (float*)(smem + OFF_CUAP);
  float* ctxpL  = (float*)(smem + OFF_CUAP);   // union (disjoint phases)
  float* redL   = (float*)(smem + OFF_RED);
  float* yL     = (float*)(smem + OFF_Y);
  u32* gatepU   = (u32*)(smem + OFF_GATEP);
  float* gatesF = (float*)(smem + OFF_GATEP);
  u32* abU      = (u32*)(smem + OFF_AB);

  // ---- one-time: stage H for this b into LDS as fp8 MFMA-A fragments ----
#pragma unroll 2
  for (int it = 0; it < 16; ++it) {
    int ch = it * 512 + tid;            // 0..8191
    int l = ch >> 4, oct = ch & 15;
    const float* src = H + (size_t)bg * (SEQL * IDIM) + l * IDIM + oct * 8;
    float4 a = *(const float4*)src;
    float4 c4 = *(const float4*)(src + 4);
    u32 lo = pk4_fp8(a.x, a.y, a.z, a.w);
    u32 hi = pk4_fp8(c4.x, c4.y, c4.z, c4.w);
    int mtile = l >> 4, lm2 = l & 15, kc = oct >> 2, q = oct & 3;
    *(uint2*)(smem + OFF_HFRAG +
              (size_t)(((mtile * 4 + kc) * 64 + q * 16 + lm2)) * 8) = make_uint2(lo, hi);
  }
  if (tid < 256) {  // carry init
    hL[tid] = emb[(size_t)bg * 512 + tid];
    cL[tid] = emb[(size_t)bg * 512 + 256 + tid];
  }
  if (tid < 128) {  // initial packed-f16 h (A rows for gate MFMA)
    const float* hp = emb + (size_t)bg * 512 + 2 * tid;
    abU[64 + tid] = pkf16(hp[0], hp[1]);
  }
  if (tid == 0) yL[0] = y0[bg];
  __syncthreads();

#pragma unroll 1
  for (int t = 0; t < TOUT; ++t) {
    f32x4 gacc[8];
#pragma unroll
    for (int i = 0; i < 8; ++i) gacc[i] = 0;

    // ===== P0: Wa-frag stage (waves 4-7) + cUa partials (waves 0-3)
    // =====     + h@U gate MFMAs (all waves; k=128..383, overlapped) =====
    if (WBF) {
      if (tid >= 256) {   // coalesced 8KB copy of pre-repacked Wa frags
        const uint4* src = (const uint4*)(WaF8 + (size_t)t * 2048);
        uint4* dst = (uint4*)(smem + OFF_GATEP);
        int id = tid - 256;
        dst[id] = src[id];
        dst[id + 256] = src[id + 256];
      }
    } else {
      if (tid >= 256) {
        int base = (tid - 256) * 4;
#pragma unroll
        for (int ii = 0; ii < 4; ++ii) {
          int id = base + ii;   // 0..1023
          int nt = id >> 8, kc = (id >> 6) & 3, l6 = id & 63;
          int lm = l6 & 15, q = l6 >> 4;
          int n = nt * 16 + lm;
          float f[8];
#pragma unroll
          for (int j = 0; j < 8; ++j)
            f[j] = Wa[((size_t)(kc * 32 + q * 8 + j) * TOUT + t) * TMP + n];
          *(uint2*)(smem + OFF_GATEP + (size_t)id * 8) =
              make_uint2(pk4_fp8(f[0], f[1], f[2], f[3]), pk4_fp8(f[4], f[5], f[6], f[7]));
        }
      }
    }
    if (tid < 256) {  // cUa partials: 8 d-parts of 32
      int j2 = tid & 31, part = tid >> 5;
      float s0 = 0.f, s1 = 0.f;
#pragma unroll 8
      for (int i = 0; i < 32; ++i) {
        int d = part * 32 + i;
        const float* up = UaF + ((size_t)d * TOUT + t) * TMP + j2 * 2;
        float c0 = cL[d];
        s0 += c0 * up[0]; s1 += c0 * up[1];
      }
      cuapL[part * 64 + j2 * 2] = s0;
      cuapL[part * 64 + j2 * 2 + 1] = s1;
    }
    if (WBF) {  // h@U: 8 nt x 8 kc f16 MFMAs, weights streamed from L2/L3
      const int q = lane >> 4;
      const char* abase = smem + OFF_AB;
#pragma unroll
      for (int i = 0; i < 8; ++i) {
        const f16x8* wb = reinterpret_cast<const f16x8*>(WUf) +
                          ((size_t)t * 64 + wv * 8 + i) * 12 * 64 + lane;
#pragma unroll
        for (int kc = 4; kc < 12; ++kc) {
          f16x8 a = *(const f16x8*)(abase + kc * 64 + q * 16);
          gacc[i] = __builtin_amdgcn_mfma_f32_16x16x32_f16(a, wb[kc * 64], gacc[i], 0, 0, 0);
        }
      }
    }
    __syncthreads();                                   // barrier A

    // ===== P1: e-pass (fp8 MFMA) + tanh/Va-dot + pv=exp2 + fused sum =====
    {
      const int lm = lane & 15, q = lane >> 4;
      float cb[4], vv[4];
#pragma unroll
      for (int nt = 0; nt < 4; ++nt) {
        float s = 0.f;
#pragma unroll
        for (int p = 0; p < 8; ++p) s += cuapL[p * 64 + nt * 16 + lm];
        cb[nt] = s + ba[t * TMP + nt * 16 + lm];
        vv[nt] = Va[(size_t)(nt * 16 + lm) * TOUT + t];
      }
      float ssum = 0.f;
#pragma unroll
      for (int mm = 0; mm < 4; ++mm) {
        int mtile = wv * 4 + mm;        // 8 waves x 4 = 32 mtiles
        f32x4 acc0 = 0, acc1 = 0, acc2 = 0, acc3 = 0;
#pragma unroll
        for (int kc = 0; kc < 4; ++kc) {
          long af = *(const long*)(smem + OFF_HFRAG +
                                   (size_t)(((mtile * 4 + kc) * 64 + lane)) * 8);
          long b0 = *(const long*)(smem + OFF_GATEP + (size_t)(((0 * 4 + kc) * 64 + lane)) * 8);
          long b1 = *(const long*)(smem + OFF_GATEP + (size_t)(((1 * 4 + kc) * 64 + lane)) * 8);
          long b2 = *(const long*)(smem + OFF_GATEP + (size_t)(((2 * 4 + kc) * 64 + lane)) * 8);
          long b3 = *(const long*)(smem + OFF_GATEP + (size_t)(((3 * 4 + kc) * 64 + lane)) * 8);
          acc0 = __builtin_amdgcn_mfma_f32_16x16x32_fp8_fp8(af, b0, acc0, 0, 0, 0);
          acc1 = __builtin_amdgcn_mfma_f32_16x16x32_fp8_fp8(af, b1, acc1, 0, 0, 0);
          acc2 = __builtin_amdgcn_mfma_f32_16x16x32_fp8_fp8(af, b2, acc2, 0, 0, 0);
          acc3 = __builtin_amdgcn_mfma_f32_16x16x32_fp8_fp8(af, b3, acc3, 0, 0, 0);
        }
        // C/D: col = nt*16 + lm, row = mtile*16 + q*4 + r
#pragma unroll
        for (int r = 0; r < 4; ++r) {
          float v = tanh_fast(acc0[r] + cb[0]) * vv[0] + tanh_fast(acc1[r] + cb[1]) * vv[1] +
                    tanh_fast(acc2[r] + cb[2]) * vv[2] + tanh_fast(acc3[r] + cb[3]) * vv[3];
          v += __shfl_xor(v, 1);
          v += __shfl_xor(v, 2);
          v += __shfl_xor(v, 4);
          v += __shfl_xor(v, 8);
          // no max-subtraction: |v|/16 bounded by sum|Va|/16 ~ 0.2 (tanh<=1);
          // softmax is shift-invariant so result is mathematically identical.
          float pv = __builtin_exp2f(v * 0.0901684400347379f);  // (1/16)*log2(e)
          ssum += pv;
          if (lm == 0) eL[mtile * 16 + q * 4 + r] = pv;
        }
      }
      ssum += __shfl_xor(ssum, 16);     // combine the 4 q-groups
      ssum += __shfl_xor(ssum, 32);
      if (lane == 0) redL[wv] = ssum;   // per-wave softmax-denominator part
    }
    __syncthreads();                                   // barrier B

    // ===== P3: ctx partials = sum_l pv_l H[l][d] (fp8 H from LDS) =====
    {
      int lsub = tid & 15, dch = (tid >> 4) & 15, half = tid >> 8;  // half 0..1
      int kc = dch >> 2, q2 = dch & 3;
      const char* hbase = smem + OFF_HFRAG;
      float a[8] = {0.f, 0.f, 0.f, 0.f, 0.f, 0.f, 0.f, 0.f};
#pragma unroll 4
      for (int i = 0; i < 16; ++i) {
        int mt = half * 16 + i;
        uint2 hv = *(const uint2*)(hbase + (size_t)(((mt * 4 + kc) * 64 + q2 * 16 + lsub)) * 8);
        float p = eL[mt * 16 + lsub];
        a[0] += p * fp8_f32<0>(hv.x); a[1] += p * fp8_f32<1>(hv.x);
        a[2] += p * fp8_f32<2>(hv.x); a[3] += p * fp8_f32<3>(hv.x);
        a[4] += p * fp8_f32<0>(hv.y); a[5] += p * fp8_f32<1>(hv.y);
        a[6] += p * fp8_f32<2>(hv.y); a[7] += p * fp8_f32<3>(hv.y);
      }
#pragma unroll
      for (int msk = 1; msk <= 8; msk <<= 1)
#pragma unroll
        for (int j = 0; j < 8; ++j) a[j] += __shfl_xor(a[j], msk);
      if (lsub == 0) {
        float* dst = &ctxpL[half * 128 + dch * 8];
#pragma unroll
        for (int j = 0; j < 8; ++j) dst[j] = a[j];
      }
    }
    __syncthreads();                                   // barrier D

    // ===== P4b: ctx@W (k=0..127) into gacc, write gates row 0 =====
    if (WBF) {
      float den = redL[0] + redL[1] + redL[2] + redL[3] +
                  redL[4] + redL[5] + redL[6] + redL[7];
      float invd = __builtin_amdgcn_rcpf(den);
      const int q = lane >> 4;
      f16x8 actx[4];
#pragma unroll
      for (int kc = 0; kc < 4; ++kc)
#pragma unroll
        for (int j = 0; j < 8; ++j) {
          int k = kc * 32 + q * 8 + j;
          actx[kc][j] = (_Float16)((ctxpL[k] + ctxpL[128 + k]) * invd);
        }
#pragma unroll
      for (int i = 0; i < 8; ++i) {
        const f16x8* wb = reinterpret_cast<const f16x8*>(WUf) +
                          ((size_t)t * 64 + wv * 8 + i) * 12 * 64 + lane;
#pragma unroll
        for (int kc = 0; kc < 4; ++kc)
          gacc[i] = __builtin_amdgcn_mfma_f32_16x16x32_f16(actx[kc], wb[kc * 64], gacc[i],
                                                           0, 0, 0);
      }
      // D row 0 (lane<16, reg 0) = gate row (A rows are broadcast copies)
      if (lane < 16) {
#pragma unroll
        for (int i = 0; i < 8; ++i)
          gatesF[(wv * 8 + i) * 16 + lane] = gacc[i][0];
      }
    } else {
      if (tid < 128) {
        float den = redL[0] + redL[1] + redL[2] + redL[3] +
                    redL[4] + redL[5] + redL[6] + redL[7];
        float invd = __builtin_amdgcn_rcpf(den);
        ctxL[tid] = (ctxpL[tid] + ctxpL[128 + tid]) * invd;
      }
      __syncthreads();   // extra barrier, fallback only (compile-time uniform)
      int gc = tid & 255, dpart = tid >> 8;
      const int c0 = gc * 4;
      float g0[4] = {0.f, 0.f, 0.f, 0.f};
      {
        const float* wpf = WF + ((size_t)(dpart * 64) * TOUT + t) * G4 + c0;
#pragma unroll 2
        for (int i4 = 0; i4 < 16; ++i4) {
          float4 cv0 = *(const float4*)&ctxL[dpart * 64 + i4 * 4];
#pragma unroll
          for (int j4 = 0; j4 < 4; ++j4) {
            float4 wf = *(const float4*)wpf;
            wpf += (size_t)TOUT * G4;
            float cc0 = (j4 == 0) ? cv0.x : (j4 == 1) ? cv0.y : (j4 == 2) ? cv0.z : cv0.w;
            g0[0] += cc0 * wf.x; g0[1] += cc0 * wf.y; g0[2] += cc0 * wf.z; g0[3] += cc0 * wf.w;
          }
        }
      }
      {
        const float* upf = UF + ((size_t)(dpart * 128) * TOUT + t) * G4 + c0;
#pragma unroll 2
        for (int i4 = 0; i4 < 32; ++i4) {
          float4 hv0 = *(const float4*)&hL[dpart * 128 + i4 * 4];
#pragma unroll
          for (int j4 = 0; j4 < 4; ++j4) {
            float4 wf = *(const float4*)upf;
            upf += (size_t)TOUT * G4;
            float hh0 = (j4 == 0) ? hv0.x : (j4 == 1) ? hv0.y : (j4 == 2) ? hv0.z : hv0.w;
            g0[0] += hh0 * wf.x; g0[1] += hh0 * wf.y; g0[2] += hh0 * wf.z; g0[3] += hh0 * wf.w;
          }
        }
      }
      *(uint2*)&gatepU[dpart * 512 + gc * 2] =
          make_uint2(pkbf(g0[0], g0[1]), pkbf(g0[2], g0[3]));
    }
    __syncthreads();                                   // barrier F

    // ===== P5: LSTM cell + y =====
    float ypart = 0.f;
    if (tid < 256) {
      float yprev = yL[0];
      float gv[4];
#pragma unroll
      for (int gi = 0; gi < 4; ++gi) {
        int col = gi * 256 + tid;
        float s;
        if (WBF) {
          s = gatesF[col];
        } else {
          int ci = col >> 1, sel = col & 1;
          s = 0.f;
#pragma unroll
          for (int p = 0; p < 2; ++p) {
            u32 u = gatepU[p * 512 + ci];
            s += sel ? bfhi(u) : bflo(u);
          }
        }
        s += bias[(size_t)t * G4 + col];
        gv[gi] = s + yprev * WyF[t * G4 + col];
      }
      float ig = sigmoid_acc(gv[0]);
      float fg = sigmoid_acc(gv[1]);
      float gg = tanh_acc(gv[2]);
      float og = sigmoid_acc(gv[3]);
      float cn = fg * cL[tid] + ig * gg;
      float hn = og * tanh_acc(cn);
      cL[tid] = cn;
      if (!WBF) hL[tid] = hn;
      out[12288 + ((size_t)bg * TOUT + t) * HS + tid] = hn;
      ypart = hn * fcw[t * HS + tid];
      float hho = __shfl_xor(hn, 1);             // pack f16 pairs for next h@U
      if (!(tid & 1)) abU[64 + (tid >> 1)] = pkf16(hn, hho);
    }
#pragma unroll
    for (int msk = 1; msk <= 32; msk <<= 1) ypart += __shfl_xor(ypart, msk);
    if (tid < 256 && lane == 0) redL[16 + wv] = ypart;   // wv 0..3 here
    __syncthreads();                                   // barrier G
    if (tid == 0) {
      float y = redL[16] + redL[17] + redL[18] + redL[19] + fcb[t];
      yL[0] = y;
      out[(size_t)bg * TOUT + t] = y;
    }
    // no trailing barrier: yL/redL[16..] consumers are >=4 barriers away;
    // next P0's GATEP write is post-G; abU-h/cL writes were pre-G.
  }
}

extern "C" void kernel_launch(void* const* d_in, const int* in_sizes, int n_in, void* d_out,
                              int out_size, void* d_ws, size_t ws_size, hipStream_t stream) {
  const float* H    = (const float*)d_in[0];
  const float* y0   = (const float*)d_in[1];
  const float* emb  = (const float*)d_in[2];
  const float* Wa   = (const float*)d_in[3];
  const float* Ua   = (const float*)d_in[4];
  const float* ba   = (const float*)d_in[5];
  const float* Va   = (const float*)d_in[6];
  const float* W    = (const float*)d_in[7];
  const float* U    = (const float*)d_in[8];
  const float* bias = (const float*)d_in[9];
  const float* Wy   = (const float*)d_in[10];
  const float* fcw  = (const float*)d_in[11];
  const float* fcb  = (const float*)d_in[12];
  float* out = (float*)d_out;

  const size_t nFrag = (size_t)TOUT * 64 * 12 * 64;   // 1,179,648 frags x 16B
  const size_t nWaFrag = (size_t)TOUT * 16 * 64;      // 24,576 frags x 8B
  const size_t need = nFrag * 16 + nWaFrag * 8;       // 19,070,976 B
  const bool usebf = (d_ws != nullptr) && (ws_size >= need);
  u32* WUf = (u32*)d_ws;
  u32* WaF8 = WUf + nFrag * 4;                        // after 18,874,368 B

  if (usebf) {
    repack_f16_kernel<<<(int)(nFrag / 256), 256, 0, stream>>>(W, U, WUf);
    repack_wa_kernel<<<(int)(nWaFrag / 256), 256, 0, stream>>>(Wa, WaF8);
  }

  hipFuncSetAttribute((const void*)lstm_attn_kernel<1>,
                      hipFuncAttributeMaxDynamicSharedMemorySize, SMEM_BYTES);
  hipFuncSetAttribute((const void*)lstm_attn_kernel<0>,
                      hipFuncAttributeMaxDynamicSharedMemorySize, SMEM_BYTES);

  if (usebf) {
    lstm_attn_kernel<1><<<NB, 512, SMEM_BYTES, stream>>>(
        H, y0, emb, Wa, Ua, ba, Va, W, U, bias, Wy, fcw, fcb, WUf, WaF8, out);
  } else {
    lstm_attn_kernel<0><<<NB, 512, SMEM_BYTES, stream>>>(
        H, y0, emb, Wa, Ua, ba, Va, W, U, bias, Wy, fcw, fcb, WUf, WaF8, out);
  }
}